// Round 10
// baseline (1991.026 us; speedup 1.0000x reference)
//
#include <hip/hip_runtime.h>
#include <hip/hip_fp16.h>

// Problem constants
#define BATCH 64
#define TLEN  256
#define HD    512
#define G3    1536          // 3*H
#define KIN0  192           // folded conv+proj K = 64 bins * 3 taps
#define XT_S  258           // padded time slots
#define XT_STRIDE (XT_S*64) // per-batch stride in xT (16512)
#define NBLOCKS 96
#define NKS_HH 16           // HD/32 k-steps
#define NKS_I0 6            // KIN0/32 k-steps
#define HS (BATCH*HD)

typedef _Float16 f16;
typedef unsigned long long u64;
typedef __attribute__((ext_vector_type(8))) _Float16 half8;
typedef __attribute__((ext_vector_type(4))) float    f32x4;

__device__ __forceinline__ f32x4 mfma16(half8 a, half8 b, f32x4 c) {
    return __builtin_amdgcn_mfma_f32_16x16x32_f16(a, b, c, 0, 0, 0);
}

// Batched device-coherent (MALL) 16B loads, no wait (proven round-6 path).
#define LD16(dst, base, OFF)                                                  \
    asm volatile("global_load_dwordx4 %0, %1, off offset:" #OFF " sc0 sc1"    \
                 : "=v"(dst) : "v"(base))

#define LDALL16(arr, base) do {                                               \
    LD16(arr[0],  base, 0);   LD16(arr[1],  base, 64);                        \
    LD16(arr[2],  base, 128); LD16(arr[3],  base, 192);                       \
    LD16(arr[4],  base, 256); LD16(arr[5],  base, 320);                       \
    LD16(arr[6],  base, 384); LD16(arr[7],  base, 448);                       \
    LD16(arr[8],  base, 512); LD16(arr[9],  base, 576);                       \
    LD16(arr[10], base, 640); LD16(arr[11], base, 704);                       \
    LD16(arr[12], base, 768); LD16(arr[13], base, 832);                       \
    LD16(arr[14], base, 896); LD16(arr[15], base, 960);                       \
} while (0)

#define WAIT_VM0()                                         \
    do {                                                   \
        asm volatile("s_waitcnt vmcnt(0)" ::: "memory");   \
        __builtin_amdgcn_sched_barrier(0);                 \
    } while (0)

// Per-(layer,slice,wave) flag, each on its own 64-B line.
#define FLAGP(flags, l, s, w) ((flags) + ((((l) * 32 + (s)) * 4 + (w)) * 16))

// ---------------- setup kernels ----------------

__global__ void fold_w3(const float* __restrict__ wih0,
                        const float* __restrict__ convw,
                        f16* __restrict__ w3) {
    int idx = blockIdx.x * 256 + threadIdx.x;
    if (idx >= G3 * KIN0) return;
    int g  = idx / KIN0;
    int kk = idx % KIN0;
    int dt = kk >> 6;
    int i  = kk & 63;
    float s = 0.f;
    for (int dr = 0; dr < 3; ++dr) {
        int r = i - dr;
        if (r < 0 || r >= 62) continue;
        const float* wrow = wih0 + (size_t)g * 3968 + r;
        #pragma unroll 8
        for (int f = 0; f < 64; ++f)
            s += wrow[f * 62] * convw[f * 9 + dr * 3 + dt];
    }
    w3[(size_t)g * KIN0 + kk] = (f16)s;
}

// wave-per-row: bias0[g] = b_ih0[g] + sum_e wih0[g,e] * convb[e/62]
__global__ void fold_bias0(const float* __restrict__ wih0,
                           const float* __restrict__ convb,
                           const float* __restrict__ bih0,
                           float* __restrict__ bias0) {
    int w    = (blockIdx.x * 256 + threadIdx.x) >> 6;
    int lane = threadIdx.x & 63;
    if (w >= G3) return;
    const float* wrow = wih0 + (size_t)w * 3968;
    float s = 0.f;
    for (int e = lane; e < 3968; e += 64) s += wrow[e] * convb[e / 62];
    #pragma unroll
    for (int o = 32; o > 0; o >>= 1) s += __shfl_down(s, o);
    if (lane == 0) bias0[w] = s + bih0[w];
}

struct Ptr5 { const float* p[5]; };

__global__ void cvt_weights(Ptr5 src, f16* __restrict__ dst) {
    int idx = blockIdx.x * 256 + threadIdx.x;
    if (idx >= 5 * G3 * HD) return;
    int m = idx / (G3 * HD), off = idx % (G3 * HD);
    dst[idx] = (f16)src.p[m][off];
}

// xT[b][s][i] = x[b, i, s-1] with zero pad at s=0 and s=257
__global__ void build_xt(const float* __restrict__ x, f16* __restrict__ xt) {
    int idx = blockIdx.x * 256 + threadIdx.x;
    if (idx >= BATCH * XT_S * 64) return;
    int b = idx / (XT_S * 64);
    int rem = idx % (XT_S * 64);
    int s = rem / 64, i = rem & 63;
    float v = 0.f;
    if (s >= 1 && s <= 256) v = x[(size_t)b * (64 * TLEN) + (size_t)i * TLEN + (s - 1)];
    xt[idx] = (f16)v;
}

// h(-1) lives at parity slot 1; zero the per-wave flag lines (6144 u32).
// MUST be launched with >= HS threads (128 blocks x 256): rounds 8/9 launched
// only 64 blocks, leaving batches 32..63 of h(-1) as workspace junk -> the
// deterministic 0.1 absmax failure.
__global__ void init_h(const float* __restrict__ h1, const float* __restrict__ h2,
                       const float* __restrict__ h3, f16* __restrict__ hbuf,
                       unsigned* __restrict__ flags) {
    int idx = blockIdx.x * 256 + threadIdx.x;
    if (idx < 6144) flags[idx] = 0u;
    if (idx >= HS) return;
    hbuf[1 * HS + idx] = (f16)h1[idx];
    hbuf[3 * HS + idx] = (f16)h2[idx];
    hbuf[5 * HS + idx] = (f16)h3[idx];
}

// ---------------- persistent diagonal-pipelined GRU ----------------
// Per-wave flags: F[l][s][w] = completed timesteps of wave w of block (l,s)
// (tile rows [16w,16w+16) x cols [16s,16s+16)). Wave (l,s,w) at timestep t:
//   main poll : F[l-1][*][w] >= t+1 (x ready)  and  F[l][*][w] >= t (h ready)
//   anti poll : F[l+1][*][w] >= t-1 (layer l+1 consumed h[t-2]; slot reuse)
// Deps reference strictly earlier completions (phi = 3t + l) -> acyclic.
// h-data and flag writes use atomic-exchange (RMW executes at the MALL).

__global__ __launch_bounds__(256, 1) void gru_persistent(
    const f16* __restrict__ xT, const f16* __restrict__ W3,
    const f16* __restrict__ wts,
    const float* __restrict__ bias0, const float* __restrict__ bhh0,
    const float* __restrict__ bih1,  const float* __restrict__ bhh1,
    const float* __restrict__ bih2,  const float* __restrict__ bhh2,
    f16* __restrict__ hb, float* __restrict__ out, unsigned* __restrict__ flags)
{
    __shared__ f16 wih_lds[3 * NKS_HH * 64 * 8];  // 49152 B (layer0 uses subset)
    __shared__ f16 whh_lds[3 * NKS_HH * 64 * 8];  // 49152 B

    const int bid   = blockIdx.x;
    const int layer = bid >> 5;       // 0..2
    const int slice = bid & 31;       // 0..31
    const int j0    = slice * 16;
    const int tid   = threadIdx.x;
    const int lane  = tid & 63;
    const int wid   = tid >> 6;
    const int b0    = wid * 16;
    const int jc    = lane & 15;
    const int kg    = lane >> 4;
    const int j     = j0 + jc;

    const int KIN  = (layer == 0) ? KIN0 : HD;
    const int nksI = (layer == 0) ? NKS_I0 : NKS_HH;
    const f16* wih_g = (layer == 0) ? W3 : (wts + (size_t)(2 * layer - 1) * (G3 * HD));
    const f16* whh_g = wts + (size_t)(2 * layer) * (G3 * HD);

    // ---- stage weights into fragment-major LDS (once) ----
    for (int e = tid; e < 3 * nksI * 64; e += 256) {
        int le = e & 63;
        int ks = (e >> 6) % nksI;
        int g  = (e >> 6) / nksI;
        int row = j0 + (le & 15);
        int col = ks * 32 + (le >> 4) * 8;
        *(half8*)&wih_lds[(size_t)e * 8] =
            *(const half8*)(wih_g + (size_t)(g * HD + row) * KIN + col);
    }
    for (int e = tid; e < 3 * NKS_HH * 64; e += 256) {
        int le = e & 63;
        int ks = (e >> 6) % NKS_HH;
        int g  = (e >> 6) / NKS_HH;
        int row = j0 + (le & 15);
        int col = ks * 32 + (le >> 4) * 8;
        *(half8*)&whh_lds[(size_t)e * 8] =
            *(const half8*)(whh_g + (size_t)(g * HD + row) * HD + col);
    }

    const float* bih = (layer == 0) ? bias0 : ((layer == 1) ? bih1 : bih2);
    const float* bhh = (layer == 0) ? bhh0  : ((layer == 1) ? bhh1 : bhh2);
    const float bRs = bih[j] + bhh[j];
    const float bZs = bih[HD + j] + bhh[HD + j];
    const float bin = bih[2 * HD + j];
    const float bhn = bhh[2 * HD + j];

    f16* hbase = hb + (size_t)layer * 2 * HS;
    const f16* xprev = (layer == 0) ? nullptr : (hb + (size_t)(layer - 1) * 2 * HS);

    // previous own-h carried in registers
    float hpr[4];
    {
        const f16* hinit = hbase + 1 * HS;   // parity of t = -1
        #pragma unroll
        for (int rr = 0; rr < 4; ++rr)
            hpr[rr] = (float)hinit[(size_t)(b0 + kg * 4 + rr) * HD + j];
    }

    __syncthreads();   // weight staging visible; only sync in the kernel

    const f16* fW = wih_lds + lane * 8;
    const f16* fH = whh_lds + lane * 8;

    // per-lane poll assignments (constant over rounds)
    const unsigned* pMain;  int mainOff;
    if (layer == 0) {
        pMain = (lane < 32) ? FLAGP(flags, 0, lane, wid) : nullptr;
        mainOff = 0;                                   // own: F >= t
    } else if (lane < 32) {
        pMain = FLAGP(flags, layer - 1, lane, wid);    // x:   F >= t+1
        mainOff = 1;
    } else {
        pMain = FLAGP(flags, layer, lane - 32, wid);   // own: F >= t
        mainOff = 0;
    }
    const unsigned* pAnti = (layer < 2 && lane < 32)
                          ? FLAGP(flags, layer + 1, lane, wid) : nullptr;
    unsigned* pMine = FLAGP(flags, layer, slice, wid);

    for (int R = 0; R < XT_S; ++R) {
        const int t = R - layer;
        const bool active = (t >= 0) && (t < TLEN);
        if (!active) continue;

        f32x4 aRx = {0.f,0.f,0.f,0.f}, aZx = {0.f,0.f,0.f,0.f}, aNi = {0.f,0.f,0.f,0.f};
        f32x4 aRh = {0.f,0.f,0.f,0.f}, aZh = {0.f,0.f,0.f,0.f}, aNh = {0.f,0.f,0.f,0.f};

        // ---- phase A: layer-0 input-side GEMM (peer-independent) ----
        if (layer == 0) {
            const f16* xb = xT + (size_t)(b0 + jc) * XT_STRIDE + (size_t)t * 64 + kg * 8;
            #pragma unroll
            for (int ks = 0; ks < NKS_I0; ++ks) {
                half8 a = *(const half8*)(xb + ks * 32);
                aRx = mfma16(a, *(const half8*)(fW + (0 * NKS_I0 + ks) * 512), aRx);
                aZx = mfma16(a, *(const half8*)(fW + (1 * NKS_I0 + ks) * 512), aZx);
                aNi = mfma16(a, *(const half8*)(fW + (2 * NKS_I0 + ks) * 512), aNi);
            }
        }

        // ---- main poll: all duty lanes poll concurrently (ballot loop) ----
        {
            bool pend = (pMain != nullptr);
            const unsigned req = (unsigned)(t + mainOff);
            while (__any(pend)) {
                if (pend)
                    pend = __hip_atomic_load(pMain, __ATOMIC_RELAXED,
                                             __HIP_MEMORY_SCOPE_AGENT) < req;
            }
            asm volatile("" ::: "memory");
        }

        // ---- issue A-operand loads (batched, one wait later) ----
        const f16* hold = hbase + ((t - 1) & 1) * HS;
        const f16* hbp  = hold + (size_t)(b0 + jc) * HD + kg * 8;
        half8 ah[NKS_HH];
        LDALL16(ah, hbp);

        half8 ax[NKS_HH];
        if (layer > 0) {
            const f16* xbp = xprev + (t & 1) * HS + (size_t)(b0 + jc) * HD + kg * 8;
            LDALL16(ax, xbp);
        }

        // ---- anti-dep poll (overlapped with loads in flight) ----
        if (layer < 2 && t >= 2) {
            bool pend = (pAnti != nullptr);
            const unsigned req = (unsigned)(t - 1);
            while (__any(pend)) {
                if (pend)
                    pend = __hip_atomic_load(pAnti, __ATOMIC_RELAXED,
                                             __HIP_MEMORY_SCOPE_AGENT) < req;
            }
            asm volatile("" ::: "memory");
        }

        WAIT_VM0();

        // ---- GEMMs ----
        if (layer > 0) {
            #pragma unroll
            for (int ks = 0; ks < NKS_HH; ++ks) {
                aRx = mfma16(ax[ks], *(const half8*)(fW + (0 * NKS_HH + ks) * 512), aRx);
                aZx = mfma16(ax[ks], *(const half8*)(fW + (1 * NKS_HH + ks) * 512), aZx);
                aNi = mfma16(ax[ks], *(const half8*)(fW + (2 * NKS_HH + ks) * 512), aNi);
                aRh = mfma16(ah[ks], *(const half8*)(fH + (0 * NKS_HH + ks) * 512), aRh);
                aZh = mfma16(ah[ks], *(const half8*)(fH + (1 * NKS_HH + ks) * 512), aZh);
                aNh = mfma16(ah[ks], *(const half8*)(fH + (2 * NKS_HH + ks) * 512), aNh);
            }
        } else {
            #pragma unroll
            for (int ks = 0; ks < NKS_HH; ++ks) {
                aRh = mfma16(ah[ks], *(const half8*)(fH + (0 * NKS_HH + ks) * 512), aRh);
                aZh = mfma16(ah[ks], *(const half8*)(fH + (1 * NKS_HH + ks) * 512), aZh);
                aNh = mfma16(ah[ks], *(const half8*)(fH + (2 * NKS_HH + ks) * 512), aNh);
            }
        }

        // ---- fused GRU epilogue ----
        float hv[4];
        #pragma unroll
        for (int rr = 0; rr < 4; ++rr) {
            float r = 1.f / (1.f + __expf(-(aRx[rr] + aRh[rr] + bRs)));
            float z = 1.f / (1.f + __expf(-(aZx[rr] + aZh[rr] + bZs)));
            float nv = aNi[rr] + bin + r * (aNh[rr] + bhn);
            float e  = __expf(2.f * nv);
            float n  = 1.f - 2.f / (e + 1.f);   // tanh, safe at +/-inf
            hv[rr] = (1.f - z) * n + z * hpr[rr];
            hpr[rr] = hv[rr];
        }

        // ---- h stores: atomic swap (executes at MALL -> ack == visible) ----
        f16* hnew = hbase + (t & 1) * HS;
        #pragma unroll
        for (int rr = 0; rr < 4; ++rr) {
            int brow = b0 + kg * 4 + rr;   // C/D row = (lane>>4)*4 + reg
            float nbv = __shfl_xor(hv[rr], 1);
            unsigned short ua = __builtin_bit_cast(unsigned short, (f16)hv[rr]);
            unsigned short ub = __builtin_bit_cast(unsigned short, (f16)nbv);
            unsigned pk = (unsigned)ua | ((unsigned)ub << 16);
            unsigned pk2 = __shfl_xor(pk, 2);
            if ((jc & 3) == 0) {
                u64 val = (u64)pk | ((u64)pk2 << 32);
                (void)__hip_atomic_exchange((u64*)(hnew + (size_t)brow * HD + j), val,
                                            __ATOMIC_RELAXED, __HIP_MEMORY_SCOPE_AGENT);
            }
        }

        // ---- per-wave publish: drain own RMWs, then flag (also RMW) ----
        WAIT_VM0();
        if (lane == 0)
            (void)__hip_atomic_exchange(pMine, (unsigned)(t + 1),
                                        __ATOMIC_RELAXED, __HIP_MEMORY_SCOPE_AGENT);

        // ---- out stores after publish (off the critical path) ----
        if (layer == 2) {
            #pragma unroll
            for (int rr = 0; rr < 4; ++rr) {
                int brow = b0 + kg * 4 + rr;
                out[(size_t)t * HS + (size_t)brow * HD + j] = hv[rr];
            }
        }
    }
}

// ---------------- launch ----------------

extern "C" void kernel_launch(void* const* d_in, const int* in_sizes, int n_in,
                              void* d_out, int out_size, void* d_ws, size_t ws_size,
                              hipStream_t stream) {
    const float* x     = (const float*)d_in[0];
    const float* h1    = (const float*)d_in[1];
    const float* h2    = (const float*)d_in[2];
    const float* h3    = (const float*)d_in[3];
    const float* convw = (const float*)d_in[4];
    const float* convb = (const float*)d_in[5];
    const float* wih0  = (const float*)d_in[6];
    const float* whh0  = (const float*)d_in[7];
    const float* bih0  = (const float*)d_in[8];
    const float* bhh0  = (const float*)d_in[9];
    const float* wih1  = (const float*)d_in[10];
    const float* whh1  = (const float*)d_in[11];
    const float* bih1  = (const float*)d_in[12];
    const float* bhh1  = (const float*)d_in[13];
    const float* wih2  = (const float*)d_in[14];
    const float* whh2  = (const float*)d_in[15];
    const float* bih2  = (const float*)d_in[16];
    const float* bhh2  = (const float*)d_in[17];

    // workspace layout (bytes)
    char* ws = (char*)d_ws;
    unsigned* flags = (unsigned*)(ws + 0);     // 384 lines * 64 B = 24576
    f16*   W3    = (f16*)(ws + 24576);         // 589824  -> 614400
    float* bias0 = (float*)(ws + 614400);      // 6144    -> 620544
    f16*   wts   = (f16*)(ws + 620544);        // 7864320 -> 8484864
    f16*   xT    = (f16*)(ws + 8484864);       // 2113536 -> 10598400
    f16*   hb    = (f16*)(ws + 10598400);      // 393216  -> 10991616

    fold_w3   <<<(G3 * KIN0 + 255) / 256, 256, 0, stream>>>(wih0, convw, W3);
    fold_bias0<<<(G3 * 64 + 255) / 256,   256, 0, stream>>>(wih0, convb, bih0, bias0);
    Ptr5 p5; p5.p[0] = whh0; p5.p[1] = wih1; p5.p[2] = whh1; p5.p[3] = wih2; p5.p[4] = whh2;
    cvt_weights<<<(5 * G3 * HD + 255) / 256, 256, 0, stream>>>(p5, wts);
    build_xt  <<<(BATCH * XT_S * 64 + 255) / 256, 256, 0, stream>>>(x, xT);
    init_h    <<<(HS + 255) / 256, 256, 0, stream>>>(h1, h2, h3, hb, flags);  // FULL HS grid

    gru_persistent<<<NBLOCKS, 256, 0, stream>>>(
        xT, W3, wts, bias0, bhh0, bih1, bhh1, bih2, bhh2,
        hb, (float*)d_out, flags);
}

// Round 11
// 1604.131 us; speedup vs baseline: 1.2412x; 1.2412x over previous
//
#include <hip/hip_runtime.h>
#include <hip/hip_fp16.h>

// Problem constants
#define BATCH 64
#define TLEN  256
#define HD    512
#define G3    1536          // 3*H
#define KIN0  192           // folded conv+proj K = 64 bins * 3 taps
#define XT_S  258           // padded time slots
#define XT_STRIDE (XT_S*64) // per-batch stride in xT (16512)
#define NBLOCKS 96
#define NKS_HH 16           // HD/32 k-steps
#define NKS_I0 6            // KIN0/32 k-steps
#define HS (BATCH*HD)
#define RING 4              // h ring depth: anti-dep gets 2 rounds of slack

typedef _Float16 f16;
typedef unsigned long long u64;
typedef __attribute__((ext_vector_type(8))) _Float16 half8;
typedef __attribute__((ext_vector_type(4))) float    f32x4;

__device__ __forceinline__ f32x4 mfma16(half8 a, half8 b, f32x4 c) {
    return __builtin_amdgcn_mfma_f32_16x16x32_f16(a, b, c, 0, 0, 0);
}

// Batched device-coherent (MALL) 16B loads, no wait.
#define LD16(dst, base, OFF)                                                  \
    asm volatile("global_load_dwordx4 %0, %1, off offset:" #OFF " sc0 sc1"    \
                 : "=v"(dst) : "v"(base))

#define LDALL16(arr, base) do {                                               \
    LD16(arr[0],  base, 0);   LD16(arr[1],  base, 64);                        \
    LD16(arr[2],  base, 128); LD16(arr[3],  base, 192);                       \
    LD16(arr[4],  base, 256); LD16(arr[5],  base, 320);                       \
    LD16(arr[6],  base, 384); LD16(arr[7],  base, 448);                       \
    LD16(arr[8],  base, 512); LD16(arr[9],  base, 576);                       \
    LD16(arr[10], base, 640); LD16(arr[11], base, 704);                       \
    LD16(arr[12], base, 768); LD16(arr[13], base, 832);                       \
    LD16(arr[14], base, 896); LD16(arr[15], base, 960);                       \
} while (0)

#define WAIT_VM0()                                         \
    do {                                                   \
        asm volatile("s_waitcnt vmcnt(0)" ::: "memory");   \
        __builtin_amdgcn_sched_barrier(0);                 \
    } while (0)

// Sub-counter for (layer, strip w, group g = slice&3), each on its own 64-B line.
#define SUBP(flags, l, w, g) ((flags) + ((((l) * 4 + (w)) * 4 + (g)) * 16))

// ---------------- setup kernels ----------------

__global__ void fold_w3(const float* __restrict__ wih0,
                        const float* __restrict__ convw,
                        f16* __restrict__ w3) {
    int idx = blockIdx.x * 256 + threadIdx.x;
    if (idx >= G3 * KIN0) return;
    int g  = idx / KIN0;
    int kk = idx % KIN0;
    int dt = kk >> 6;
    int i  = kk & 63;
    float s = 0.f;
    for (int dr = 0; dr < 3; ++dr) {
        int r = i - dr;
        if (r < 0 || r >= 62) continue;
        const float* wrow = wih0 + (size_t)g * 3968 + r;
        #pragma unroll 8
        for (int f = 0; f < 64; ++f)
            s += wrow[f * 62] * convw[f * 9 + dr * 3 + dt];
    }
    w3[(size_t)g * KIN0 + kk] = (f16)s;
}

// wave-per-row: bias0[g] = b_ih0[g] + sum_e wih0[g,e] * convb[e/62]
__global__ void fold_bias0(const float* __restrict__ wih0,
                           const float* __restrict__ convb,
                           const float* __restrict__ bih0,
                           float* __restrict__ bias0) {
    int w    = (blockIdx.x * 256 + threadIdx.x) >> 6;
    int lane = threadIdx.x & 63;
    if (w >= G3) return;
    const float* wrow = wih0 + (size_t)w * 3968;
    float s = 0.f;
    for (int e = lane; e < 3968; e += 64) s += wrow[e] * convb[e / 62];
    #pragma unroll
    for (int o = 32; o > 0; o >>= 1) s += __shfl_down(s, o);
    if (lane == 0) bias0[w] = s + bih0[w];
}

struct Ptr5 { const float* p[5]; };

__global__ void cvt_weights(Ptr5 src, f16* __restrict__ dst) {
    int idx = blockIdx.x * 256 + threadIdx.x;
    if (idx >= 5 * G3 * HD) return;
    int m = idx / (G3 * HD), off = idx % (G3 * HD);
    dst[idx] = (f16)src.p[m][off];
}

// xT[b][s][i] = x[b, i, s-1] with zero pad at s=0 and s=257
__global__ void build_xt(const float* __restrict__ x, f16* __restrict__ xt) {
    int idx = blockIdx.x * 256 + threadIdx.x;
    if (idx >= BATCH * XT_S * 64) return;
    int b = idx / (XT_S * 64);
    int rem = idx % (XT_S * 64);
    int s = rem / 64, i = rem & 63;
    float v = 0.f;
    if (s >= 1 && s <= 256) v = x[(size_t)b * (64 * TLEN) + (size_t)i * TLEN + (s - 1)];
    xt[idx] = (f16)v;
}

// h(-1) lives at ring slot 3; zero the counter lines.
// MUST cover all HS elements (128 blocks x 256) — round-8/9 lesson.
__global__ void init_h(const float* __restrict__ h1, const float* __restrict__ h2,
                       const float* __restrict__ h3, f16* __restrict__ hbuf,
                       unsigned* __restrict__ flags) {
    int idx = blockIdx.x * 256 + threadIdx.x;
    if (idx < 1024) flags[idx] = 0u;
    if (idx >= HS) return;
    hbuf[(0 * RING + 3) * (size_t)HS + idx] = (f16)h1[idx];
    hbuf[(1 * RING + 3) * (size_t)HS + idx] = (f16)h2[idx];
    hbuf[(2 * RING + 3) * (size_t)HS + idx] = (f16)h3[idx];
}

// ---------------- persistent diagonal-pipelined GRU ----------------
// Aggregated sub-counters: cnt[l][w][g] = sum over slices s (s&3==g) of
// completed timesteps of wave (l,s,w). Own-poll Sigma>=8t per group enforces
// layer-wide lockstep (max-min<=1), which makes the group check exact:
// Sigma_g >= 8t  <=>  all 8 members >= t (a t-1 member caps Sigma at 8t-1).
// Wave (l,s,w) at step t:
//   ballotA : x     cnt[l-1][w][*] >= 8(t+1)   (l>0)
//             anti  cnt[l+1][w][*] >= 8(t-3)   (l<2, t>=4; RING=4 slack)
//   ballotB : own   cnt[l][w][*]   >= 8t
// x-GEMM runs between ballotA and ballotB (hides own-publish latency).
// h stores = atomic-exchange (ack == MALL-committed); publish = fetch_add.

__global__ __launch_bounds__(256, 1) void gru_persistent(
    const f16* __restrict__ xT, const f16* __restrict__ W3,
    const f16* __restrict__ wts,
    const float* __restrict__ bias0, const float* __restrict__ bhh0,
    const float* __restrict__ bih1,  const float* __restrict__ bhh1,
    const float* __restrict__ bih2,  const float* __restrict__ bhh2,
    f16* __restrict__ hb, float* __restrict__ out, unsigned* __restrict__ flags)
{
    __shared__ f16 wih_lds[3 * NKS_HH * 64 * 8];  // 49152 B (layer0 uses subset)
    __shared__ f16 whh_lds[3 * NKS_HH * 64 * 8];  // 49152 B

    const int bid   = blockIdx.x;
    const int layer = bid >> 5;       // 0..2
    const int slice = bid & 31;       // 0..31
    const int j0    = slice * 16;
    const int tid   = threadIdx.x;
    const int lane  = tid & 63;
    const int wid   = tid >> 6;       // batch strip
    const int b0    = wid * 16;
    const int jc    = lane & 15;
    const int kg    = lane >> 4;
    const int j     = j0 + jc;

    const int KIN  = (layer == 0) ? KIN0 : HD;
    const int nksI = (layer == 0) ? NKS_I0 : NKS_HH;
    const f16* wih_g = (layer == 0) ? W3 : (wts + (size_t)(2 * layer - 1) * (G3 * HD));
    const f16* whh_g = wts + (size_t)(2 * layer) * (G3 * HD);

    // ---- stage weights into fragment-major LDS (once) ----
    for (int e = tid; e < 3 * nksI * 64; e += 256) {
        int le = e & 63;
        int ks = (e >> 6) % nksI;
        int g  = (e >> 6) / nksI;
        int row = j0 + (le & 15);
        int col = ks * 32 + (le >> 4) * 8;
        *(half8*)&wih_lds[(size_t)e * 8] =
            *(const half8*)(wih_g + (size_t)(g * HD + row) * KIN + col);
    }
    for (int e = tid; e < 3 * NKS_HH * 64; e += 256) {
        int le = e & 63;
        int ks = (e >> 6) % NKS_HH;
        int g  = (e >> 6) / NKS_HH;
        int row = j0 + (le & 15);
        int col = ks * 32 + (le >> 4) * 8;
        *(half8*)&whh_lds[(size_t)e * 8] =
            *(const half8*)(whh_g + (size_t)(g * HD + row) * HD + col);
    }

    const float* bih = (layer == 0) ? bias0 : ((layer == 1) ? bih1 : bih2);
    const float* bhh = (layer == 0) ? bhh0  : ((layer == 1) ? bhh1 : bhh2);
    const float bRs = bih[j] + bhh[j];
    const float bZs = bih[HD + j] + bhh[HD + j];
    const float bin = bih[2 * HD + j];
    const float bhn = bhh[2 * HD + j];

    f16* hbase = hb + (size_t)layer * RING * HS;
    const f16* xprev = (layer == 0) ? nullptr : (hb + (size_t)(layer - 1) * RING * HS);

    // previous own-h carried in registers
    float hpr[4];
    {
        const f16* hinit = hbase + 3 * (size_t)HS;   // ring slot of t = -1
        #pragma unroll
        for (int rr = 0; rr < 4; ++rr)
            hpr[rr] = (float)hinit[(size_t)(b0 + kg * 4 + rr) * HD + j];
    }

    __syncthreads();   // weight staging visible; only block sync in the kernel

    const f16* fW = wih_lds + lane * 8;
    const f16* fH = whh_lds + lane * 8;

    // poll targets (constant over rounds)
    const unsigned* pX    = (layer > 0 && lane < 4)
                          ? SUBP(flags, layer - 1, wid, lane) : nullptr;
    const unsigned* pAnti = (layer < 2 && lane >= 4 && lane < 8)
                          ? SUBP(flags, layer + 1, wid, lane - 4) : nullptr;
    const unsigned* pOwn  = (lane < 4) ? SUBP(flags, layer, wid, lane) : nullptr;
    unsigned* pAdd = SUBP(flags, layer, wid, slice & 3);

    for (int R = 0; R < XT_S; ++R) {
        const int t = R - layer;
        if (t < 0 || t >= TLEN) continue;

        f32x4 aRx = {0.f,0.f,0.f,0.f}, aZx = {0.f,0.f,0.f,0.f}, aNi = {0.f,0.f,0.f,0.f};
        f32x4 aRh = {0.f,0.f,0.f,0.f}, aZh = {0.f,0.f,0.f,0.f}, aNh = {0.f,0.f,0.f,0.f};

        // ---- layer-0 phase A: xT-side GEMM (peer-independent) ----
        if (layer == 0) {
            const f16* xb = xT + (size_t)(b0 + jc) * XT_STRIDE + (size_t)t * 64 + kg * 8;
            #pragma unroll
            for (int ks = 0; ks < NKS_I0; ++ks) {
                half8 a = *(const half8*)(xb + ks * 32);
                aRx = mfma16(a, *(const half8*)(fW + (0 * NKS_I0 + ks) * 512), aRx);
                aZx = mfma16(a, *(const half8*)(fW + (1 * NKS_I0 + ks) * 512), aZx);
                aNi = mfma16(a, *(const half8*)(fW + (2 * NKS_I0 + ks) * 512), aNi);
            }
        }

        // ---- ballotA: x ready (l>0) + anti-dep (l<2, t>=4) ----
        {
            bool pend; unsigned req;
            if (lane < 4)      { pend = (pX != nullptr);
                                 req  = 8u * (unsigned)(t + 1); }
            else if (lane < 8) { pend = (pAnti != nullptr) && (t >= 4);
                                 req  = 8u * (unsigned)(t - 3); }
            else               { pend = false; req = 0; }
            const unsigned* p = (lane < 4) ? pX : pAnti;
            while (__any(pend)) {
                if (pend)
                    pend = __hip_atomic_load(p, __ATOMIC_RELAXED,
                                             __HIP_MEMORY_SCOPE_AGENT) < req;
            }
            asm volatile("" ::: "memory");
        }

        // ---- l>0: load x, x-GEMM (own publishes land meanwhile) ----
        if (layer > 0) {
            const f16* xbp = xprev + (size_t)(t & 3) * HS + (size_t)(b0 + jc) * HD + kg * 8;
            half8 ax[NKS_HH];
            LDALL16(ax, xbp);
            WAIT_VM0();
            #pragma unroll
            for (int ks = 0; ks < NKS_HH; ++ks) {
                aRx = mfma16(ax[ks], *(const half8*)(fW + (0 * NKS_HH + ks) * 512), aRx);
                aZx = mfma16(ax[ks], *(const half8*)(fW + (1 * NKS_HH + ks) * 512), aZx);
                aNi = mfma16(ax[ks], *(const half8*)(fW + (2 * NKS_HH + ks) * 512), aNi);
            }
        }

        // ---- ballotB: own h_{t-1} ready ----
        {
            bool pend = (pOwn != nullptr) && (t > 0);
            const unsigned req = 8u * (unsigned)t;
            while (__any(pend)) {
                if (pend)
                    pend = __hip_atomic_load(pOwn, __ATOMIC_RELAXED,
                                             __HIP_MEMORY_SCOPE_AGENT) < req;
            }
            asm volatile("" ::: "memory");
        }

        // ---- load own h, h-GEMM ----
        {
            const f16* hbp = hbase + (size_t)((t - 1) & 3) * HS
                           + (size_t)(b0 + jc) * HD + kg * 8;
            half8 ah[NKS_HH];
            LDALL16(ah, hbp);
            WAIT_VM0();
            #pragma unroll
            for (int ks = 0; ks < NKS_HH; ++ks) {
                aRh = mfma16(ah[ks], *(const half8*)(fH + (0 * NKS_HH + ks) * 512), aRh);
                aZh = mfma16(ah[ks], *(const half8*)(fH + (1 * NKS_HH + ks) * 512), aZh);
                aNh = mfma16(ah[ks], *(const half8*)(fH + (2 * NKS_HH + ks) * 512), aNh);
            }
        }

        // ---- fused GRU epilogue ----
        float hv[4];
        #pragma unroll
        for (int rr = 0; rr < 4; ++rr) {
            float r = 1.f / (1.f + __expf(-(aRx[rr] + aRh[rr] + bRs)));
            float z = 1.f / (1.f + __expf(-(aZx[rr] + aZh[rr] + bZs)));
            float nv = aNi[rr] + bin + r * (aNh[rr] + bhn);
            float e  = __expf(2.f * nv);
            float n  = 1.f - 2.f / (e + 1.f);   // tanh, safe at +/-inf
            hv[rr] = (1.f - z) * n + z * hpr[rr];
            hpr[rr] = hv[rr];
        }

        // ---- h stores: atomic swap (executes at MALL -> ack == visible) ----
        f16* hnew = hbase + (size_t)(t & 3) * HS;
        #pragma unroll
        for (int rr = 0; rr < 4; ++rr) {
            int brow = b0 + kg * 4 + rr;   // C/D row = (lane>>4)*4 + reg
            float nbv = __shfl_xor(hv[rr], 1);
            unsigned short ua = __builtin_bit_cast(unsigned short, (f16)hv[rr]);
            unsigned short ub = __builtin_bit_cast(unsigned short, (f16)nbv);
            unsigned pk = (unsigned)ua | ((unsigned)ub << 16);
            unsigned pk2 = __shfl_xor(pk, 2);
            if ((jc & 3) == 0) {
                u64 val = (u64)pk | ((u64)pk2 << 32);
                (void)__hip_atomic_exchange((u64*)(hnew + (size_t)brow * HD + j), val,
                                            __ATOMIC_RELAXED, __HIP_MEMORY_SCOPE_AGENT);
            }
        }

        // ---- per-wave publish: drain RMWs, then one counter add ----
        WAIT_VM0();
        if (lane == 0)
            (void)__hip_atomic_fetch_add(pAdd, 1u, __ATOMIC_RELAXED,
                                         __HIP_MEMORY_SCOPE_AGENT);

        // ---- out stores after publish (off the critical path) ----
        if (layer == 2) {
            #pragma unroll
            for (int rr = 0; rr < 4; ++rr) {
                int brow = b0 + kg * 4 + rr;
                out[(size_t)t * HS + (size_t)brow * HD + j] = hv[rr];
            }
        }
    }
}

// ---------------- launch ----------------

extern "C" void kernel_launch(void* const* d_in, const int* in_sizes, int n_in,
                              void* d_out, int out_size, void* d_ws, size_t ws_size,
                              hipStream_t stream) {
    const float* x     = (const float*)d_in[0];
    const float* h1    = (const float*)d_in[1];
    const float* h2    = (const float*)d_in[2];
    const float* h3    = (const float*)d_in[3];
    const float* convw = (const float*)d_in[4];
    const float* convb = (const float*)d_in[5];
    const float* wih0  = (const float*)d_in[6];
    const float* whh0  = (const float*)d_in[7];
    const float* bih0  = (const float*)d_in[8];
    const float* bhh0  = (const float*)d_in[9];
    const float* wih1  = (const float*)d_in[10];
    const float* whh1  = (const float*)d_in[11];
    const float* bih1  = (const float*)d_in[12];
    const float* bhh1  = (const float*)d_in[13];
    const float* wih2  = (const float*)d_in[14];
    const float* whh2  = (const float*)d_in[15];
    const float* bih2  = (const float*)d_in[16];
    const float* bhh2  = (const float*)d_in[17];

    // workspace layout (bytes)
    char* ws = (char*)d_ws;
    unsigned* flags = (unsigned*)(ws + 0);     // 48 counter lines * 64 B = 3072 (pad 4096)
    f16*   W3    = (f16*)(ws + 4096);          // 589824  -> 593920
    float* bias0 = (float*)(ws + 593920);      // 6144    -> 600064
    f16*   wts   = (f16*)(ws + 600064);        // 7864320 -> 8464384
    f16*   xT    = (f16*)(ws + 8464384);       // 2113536 -> 10577920
    f16*   hb    = (f16*)(ws + 10577920);      // 3*4*HS*2 = 786432 -> 11364352

    fold_w3   <<<(G3 * KIN0 + 255) / 256, 256, 0, stream>>>(wih0, convw, W3);
    fold_bias0<<<(G3 * 64 + 255) / 256,   256, 0, stream>>>(wih0, convb, bih0, bias0);
    Ptr5 p5; p5.p[0] = whh0; p5.p[1] = wih1; p5.p[2] = whh1; p5.p[3] = wih2; p5.p[4] = whh2;
    cvt_weights<<<(5 * G3 * HD + 255) / 256, 256, 0, stream>>>(p5, wts);
    build_xt  <<<(BATCH * XT_S * 64 + 255) / 256, 256, 0, stream>>>(x, xT);
    init_h    <<<(HS + 255) / 256, 256, 0, stream>>>(h1, h2, h3, hb, flags);  // FULL HS grid

    gru_persistent<<<NBLOCKS, 256, 0, stream>>>(
        xT, W3, wts, bias0, bhh0, bih1, bhh1, bih2, bhh2,
        hb, (float*)d_out, flags);
}